// Round 1
// baseline (4003.029 us; speedup 1.0000x reference)
//
#include <hip/hip_runtime.h>

static constexpr int D = 128;

// Copy [virus_emb; drug_emb] into h (ws) and acc (d_out) in one pass.
__global__ void init_copy(const float4* __restrict__ vsrc,
                          const float4* __restrict__ dsrc,
                          float4* __restrict__ h,
                          float4* __restrict__ acc,
                          long nv4, long total4) {
    long i = (long)blockIdx.x * blockDim.x + threadIdx.x;
    long stride = (long)gridDim.x * blockDim.x;
    for (; i < total4; i += stride) {
        float4 v = (i < nv4) ? vsrc[i] : dsrc[i - nv4];
        h[i] = v;
        acc[i] = v;
    }
}

// One 64-lane wave per edge. Each lane handles 2 of the 128 features.
// Gather h[col] (coalesced 512B per wave), scale by edge_val, atomicAdd
// into h_next[row].
__global__ void spmm_scatter(const int* __restrict__ erow,
                             const int* __restrict__ ecol,
                             const float* __restrict__ eval,
                             const float* __restrict__ h,
                             float* __restrict__ hnext,
                             int E) {
    long tid = (long)blockIdx.x * blockDim.x + threadIdx.x;
    int e = (int)(tid >> 6);
    if (e >= E) return;
    int lane = (int)(tid & 63);
    int r = erow[e];
    int c = ecol[e];
    float w = eval[e];
    const float2* src = reinterpret_cast<const float2*>(h + (long)c * D);
    float2 m = src[lane];
    float* dst = hnext + (long)r * D + lane * 2;
    atomicAdd(dst, w * m.x);
    atomicAdd(dst + 1, w * m.y);
}

// acc = (acc + b) * s   (s = 1 for intermediate layers, 0.25 for the last)
__global__ void add_scale(float4* __restrict__ acc,
                          const float4* __restrict__ b,
                          float s, long total4) {
    long i = (long)blockIdx.x * blockDim.x + threadIdx.x;
    long stride = (long)gridDim.x * blockDim.x;
    for (; i < total4; i += stride) {
        float4 a = acc[i];
        float4 v = b[i];
        a.x = (a.x + v.x) * s;
        a.y = (a.y + v.y) * s;
        a.z = (a.z + v.z) * s;
        a.w = (a.w + v.w) * s;
        acc[i] = a;
    }
}

extern "C" void kernel_launch(void* const* d_in, const int* in_sizes, int n_in,
                              void* d_out, int out_size, void* d_ws, size_t ws_size,
                              hipStream_t stream) {
    const int*   erow = (const int*)d_in[0];
    const int*   ecol = (const int*)d_in[1];
    const float* eval = (const float*)d_in[2];
    const float* vemb = (const float*)d_in[3];
    const float* demb = (const float*)d_in[4];

    int  E   = in_sizes[0];
    long nvD = in_sizes[3];
    long ndD = in_sizes[4];
    long ND  = nvD + ndD;          // == out_size == 100000*128

    float* out  = (float*)d_out;   // running accumulator, becomes final
    float* bufA = (float*)d_ws;    // h ping
    float* bufB = bufA + ND;       // h pong

    long total4 = ND / 4;
    long nv4    = nvD / 4;

    const int blk = 256;
    const int copyGrid = 2048;     // grid-stride

    hipLaunchKernelGGL(init_copy, dim3(copyGrid), dim3(blk), 0, stream,
                       (const float4*)vemb, (const float4*)demb,
                       (float4*)bufA, (float4*)out, nv4, total4);

    float* cur = bufA;
    float* nxt = bufB;
    for (int l = 0; l < 3; ++l) {
        hipMemsetAsync(nxt, 0, (size_t)ND * sizeof(float), stream);

        long threads = (long)E * 64;
        int  sgrid   = (int)((threads + blk - 1) / blk);
        hipLaunchKernelGGL(spmm_scatter, dim3(sgrid), dim3(blk), 0, stream,
                           erow, ecol, eval, cur, nxt, E);

        float s = (l == 2) ? 0.25f : 1.0f;
        hipLaunchKernelGGL(add_scale, dim3(copyGrid), dim3(blk), 0, stream,
                           (float4*)out, (const float4*)nxt, s, total4);

        float* t = cur; cur = nxt; nxt = t;
    }
}

// Round 2
// 665.924 us; speedup vs baseline: 6.0112x; 6.0112x over previous
//
#include <hip/hip_runtime.h>

static constexpr int D = 128;

// ---------------- init: h = x, acc = x ----------------
__global__ void init_copy(const float4* __restrict__ vsrc,
                          const float4* __restrict__ dsrc,
                          float4* __restrict__ h,
                          float4* __restrict__ acc,
                          long nv4, long total4) {
    long i = (long)blockIdx.x * blockDim.x + threadIdx.x;
    long stride = (long)gridDim.x * blockDim.x;
    for (; i < total4; i += stride) {
        float4 v = (i < nv4) ? vsrc[i] : dsrc[i - nv4];
        h[i] = v;
        acc[i] = v;
    }
}

// ---------------- CSR build ----------------
__global__ void hist_deg(const int* __restrict__ erow, int* __restrict__ deg, int E) {
    int e = blockIdx.x * blockDim.x + threadIdx.x;
    if (e < E) atomicAdd(&deg[erow[e]], 1);
}

// block-level exclusive scan of deg -> row_ptr (partial), block totals -> partials
__global__ void scan_block(const int* __restrict__ deg, int* __restrict__ excl_out,
                           int* __restrict__ partials, int N) {
    __shared__ int sm[1024];
    int t = threadIdx.x;
    int i = blockIdx.x * 1024 + t;
    int v = (i < N) ? deg[i] : 0;
    sm[t] = v;
    __syncthreads();
    for (int off = 1; off < 1024; off <<= 1) {
        int x = sm[t];
        int y = (t >= off) ? sm[t - off] : 0;
        __syncthreads();
        sm[t] = x + y;
        __syncthreads();
    }
    if (i < N) excl_out[i] = sm[t] - v;          // exclusive
    if (t == 1023) partials[blockIdx.x] = sm[1023];
}

// single-block exclusive scan of partials (nb <= 1024)
__global__ void scan_partials(int* __restrict__ partials, int nb) {
    __shared__ int sm[1024];
    int t = threadIdx.x;
    int v = (t < nb) ? partials[t] : 0;
    sm[t] = v;
    __syncthreads();
    for (int off = 1; off < 1024; off <<= 1) {
        int x = sm[t];
        int y = (t >= off) ? sm[t - off] : 0;
        __syncthreads();
        sm[t] = x + y;
        __syncthreads();
    }
    if (t < nb) partials[t] = sm[t] - v;
}

// row_ptr += partials[block]; cursor = row_ptr; dinv = rsqrt(deg); row_ptr[N]=E
__global__ void finalize_rows(const int* __restrict__ deg, int* __restrict__ row_ptr,
                              const int* __restrict__ partials, int* __restrict__ cursor,
                              float* __restrict__ dinv, int N, int E) {
    int i = blockIdx.x * 1024 + threadIdx.x;
    if (i < N) {
        int rp = row_ptr[i] + partials[blockIdx.x];
        row_ptr[i] = rp;
        cursor[i] = rp;
        int dg = deg[i];
        dinv[i] = (dg > 0) ? rsqrtf((float)dg) : 0.0f;
    }
    if (i == 0 && blockIdx.x == 0) row_ptr[N] = E;
}

__global__ void scatter_csr(const int* __restrict__ erow, const int* __restrict__ ecol,
                            int* __restrict__ cursor, int* __restrict__ col_s, int E) {
    int e = blockIdx.x * blockDim.x + threadIdx.x;
    if (e >= E) return;
    int pos = atomicAdd(&cursor[erow[e]], 1);
    col_s[pos] = ecol[e];
}

// ---------------- gather SpMM: one wave per row ----------------
// h_next[r] = dinv[r] * sum_c dinv[c]*h[c];  acc[r] = (acc[r]+h_next[r])*scale
__global__ void spmm_csr(const int* __restrict__ row_ptr, const int* __restrict__ col_s,
                         const float* __restrict__ dinv, const float2* __restrict__ h,
                         float2* __restrict__ hnext, float2* __restrict__ acc,
                         float scale, int writeH, int N) {
    int gid = blockIdx.x * blockDim.x + threadIdx.x;
    int r = gid >> 6;
    if (r >= N) return;
    int lane = gid & 63;
    int start = row_ptr[r], end = row_ptr[r + 1];
    float sx = 0.0f, sy = 0.0f;
    int j = start;
    for (; j + 1 < end; j += 2) {
        int c0 = col_s[j], c1 = col_s[j + 1];
        float w0 = dinv[c0], w1 = dinv[c1];
        float2 v0 = h[(long)c0 * 64 + lane];
        float2 v1 = h[(long)c1 * 64 + lane];
        sx += w0 * v0.x + w1 * v1.x;
        sy += w0 * v0.y + w1 * v1.y;
    }
    if (j < end) {
        int c = col_s[j];
        float w = dinv[c];
        float2 v = h[(long)c * 64 + lane];
        sx += w * v.x;
        sy += w * v.y;
    }
    float dr = dinv[r];
    sx *= dr; sy *= dr;
    long o = (long)r * 64 + lane;
    if (writeH) hnext[o] = make_float2(sx, sy);
    float2 a = acc[o];
    a.x = (a.x + sx) * scale;
    a.y = (a.y + sy) * scale;
    acc[o] = a;
}

// ---------------- fallback (round-1 atomic path) ----------------
__global__ void spmm_scatter(const int* __restrict__ erow, const int* __restrict__ ecol,
                             const float* __restrict__ eval, const float* __restrict__ h,
                             float* __restrict__ hnext, int E) {
    long tid = (long)blockIdx.x * blockDim.x + threadIdx.x;
    int e = (int)(tid >> 6);
    if (e >= E) return;
    int lane = (int)(tid & 63);
    int r = erow[e], c = ecol[e];
    float w = eval[e];
    const float2* src = reinterpret_cast<const float2*>(h + (long)c * D);
    float2 m = src[lane];
    float* dst = hnext + (long)r * D + lane * 2;
    atomicAdd(dst, w * m.x);
    atomicAdd(dst + 1, w * m.y);
}

__global__ void add_scale(float4* __restrict__ acc, const float4* __restrict__ b,
                          float s, long total4) {
    long i = (long)blockIdx.x * blockDim.x + threadIdx.x;
    long stride = (long)gridDim.x * blockDim.x;
    for (; i < total4; i += stride) {
        float4 a = acc[i];
        float4 v = b[i];
        a.x = (a.x + v.x) * s;
        a.y = (a.y + v.y) * s;
        a.z = (a.z + v.z) * s;
        a.w = (a.w + v.w) * s;
        acc[i] = a;
    }
}

extern "C" void kernel_launch(void* const* d_in, const int* in_sizes, int n_in,
                              void* d_out, int out_size, void* d_ws, size_t ws_size,
                              hipStream_t stream) {
    const int*   erow = (const int*)d_in[0];
    const int*   ecol = (const int*)d_in[1];
    const float* eval = (const float*)d_in[2];
    const float* vemb = (const float*)d_in[3];
    const float* demb = (const float*)d_in[4];

    int  E   = in_sizes[0];
    long nvD = in_sizes[3];
    long ndD = in_sizes[4];
    long ND  = nvD + ndD;
    int  N   = (int)(ND / D);

    float* out = (float*)d_out;

    // ws layout
    char* w = (char*)d_ws;
    float* bufA = (float*)w;  w += (size_t)ND * sizeof(float);
    float* bufB = (float*)w;  w += (size_t)ND * sizeof(float);
    int* col_s   = (int*)w;   w += (size_t)E * sizeof(int);
    int* row_ptr = (int*)w;   w += (size_t)(N + 1) * sizeof(int);
    int* cursor  = (int*)w;   w += (size_t)N * sizeof(int);
    int* deg     = (int*)w;   w += (size_t)N * sizeof(int);
    int* partials = (int*)w;  w += 1024 * sizeof(int);
    float* dinv  = (float*)w; w += (size_t)N * sizeof(float);
    size_t needed = (size_t)(w - (char*)d_ws);

    long total4 = ND / 4;
    long nv4    = nvD / 4;
    const int blk = 256;
    const int copyGrid = 2048;

    if (needed <= ws_size && N <= 1024 * 1024) {
        // ---------- CSR build ----------
        hipMemsetAsync(deg, 0, (size_t)N * sizeof(int), stream);
        int egrid = (E + blk - 1) / blk;
        hipLaunchKernelGGL(hist_deg, dim3(egrid), dim3(blk), 0, stream, erow, deg, E);

        int nb = (N + 1023) / 1024;   // 98 for N=100000, must be <=1024
        hipLaunchKernelGGL(scan_block, dim3(nb), dim3(1024), 0, stream,
                           deg, row_ptr, partials, N);
        hipLaunchKernelGGL(scan_partials, dim3(1), dim3(1024), 0, stream, partials, nb);
        hipLaunchKernelGGL(finalize_rows, dim3(nb), dim3(1024), 0, stream,
                           deg, row_ptr, partials, cursor, dinv, N, E);
        hipLaunchKernelGGL(scatter_csr, dim3(egrid), dim3(blk), 0, stream,
                           erow, ecol, cursor, col_s, E);

        // ---------- init ----------
        hipLaunchKernelGGL(init_copy, dim3(copyGrid), dim3(blk), 0, stream,
                           (const float4*)vemb, (const float4*)demb,
                           (float4*)bufA, (float4*)out, nv4, total4);

        // ---------- 3 layers, gather SpMM with fused acc ----------
        float* cur = bufA;
        float* nxt = bufB;
        int rgrid = (N * 64 + blk - 1) / blk;   // one wave per row
        for (int l = 0; l < 3; ++l) {
            float s = (l == 2) ? 0.25f : 1.0f;
            int writeH = (l < 2) ? 1 : 0;
            hipLaunchKernelGGL(spmm_csr, dim3(rgrid), dim3(blk), 0, stream,
                               row_ptr, col_s, dinv, (const float2*)cur,
                               (float2*)nxt, (float2*)out, s, writeH, N);
            float* t = cur; cur = nxt; nxt = t;
        }
    } else {
        // ---------- fallback: atomic scatter path ----------
        hipLaunchKernelGGL(init_copy, dim3(copyGrid), dim3(blk), 0, stream,
                           (const float4*)vemb, (const float4*)demb,
                           (float4*)bufA, (float4*)out, nv4, total4);
        float* cur = bufA;
        float* nxt = bufB;
        for (int l = 0; l < 3; ++l) {
            hipMemsetAsync(nxt, 0, (size_t)ND * sizeof(float), stream);
            long threads = (long)E * 64;
            int  sgrid   = (int)((threads + blk - 1) / blk);
            hipLaunchKernelGGL(spmm_scatter, dim3(sgrid), dim3(blk), 0, stream,
                               erow, ecol, eval, cur, nxt, E);
            float s = (l == 2) ? 0.25f : 1.0f;
            hipLaunchKernelGGL(add_scale, dim3(copyGrid), dim3(blk), 0, stream,
                               (float4*)out, (const float4*)nxt, s, total4);
            float* t = cur; cur = nxt; nxt = t;
        }
    }
}

// Round 3
// 460.364 us; speedup vs baseline: 8.6954x; 1.4465x over previous
//
#include <hip/hip_runtime.h>
#include <hip/hip_fp16.h>

static constexpr int D = 128;

// ---------------- CSR build ----------------
__global__ void hist_deg(const int* __restrict__ erow, int* __restrict__ deg, int E) {
    int e = blockIdx.x * blockDim.x + threadIdx.x;
    if (e < E) atomicAdd(&deg[erow[e]], 1);
}

__global__ void scan_block(const int* __restrict__ deg, int* __restrict__ excl_out,
                           int* __restrict__ partials, int N) {
    __shared__ int sm[1024];
    int t = threadIdx.x;
    int i = blockIdx.x * 1024 + t;
    int v = (i < N) ? deg[i] : 0;
    sm[t] = v;
    __syncthreads();
    for (int off = 1; off < 1024; off <<= 1) {
        int x = sm[t];
        int y = (t >= off) ? sm[t - off] : 0;
        __syncthreads();
        sm[t] = x + y;
        __syncthreads();
    }
    if (i < N) excl_out[i] = sm[t] - v;          // exclusive
    if (t == 1023) partials[blockIdx.x] = sm[1023];
}

__global__ void scan_partials(int* __restrict__ partials, int nb) {
    __shared__ int sm[1024];
    int t = threadIdx.x;
    int v = (t < nb) ? partials[t] : 0;
    sm[t] = v;
    __syncthreads();
    for (int off = 1; off < 1024; off <<= 1) {
        int x = sm[t];
        int y = (t >= off) ? sm[t - off] : 0;
        __syncthreads();
        sm[t] = x + y;
        __syncthreads();
    }
    if (t < nb) partials[t] = sm[t] - v;
}

__global__ void finalize_rows(const int* __restrict__ deg, int* __restrict__ row_ptr,
                              const int* __restrict__ partials, int* __restrict__ cursor,
                              float* __restrict__ dinv, int N, int E) {
    int i = blockIdx.x * 1024 + threadIdx.x;
    if (i < N) {
        int rp = row_ptr[i] + partials[blockIdx.x];
        row_ptr[i] = rp;
        cursor[i] = rp;
        int dg = deg[i];
        dinv[i] = (dg > 0) ? rsqrtf((float)dg) : 0.0f;
    }
    if (i == 0 && blockIdx.x == 0) row_ptr[N] = E;
}

__global__ void scatter_csr(const int* __restrict__ erow, const int* __restrict__ ecol,
                            int* __restrict__ cursor, int* __restrict__ col_s, int E) {
    int e = blockIdx.x * blockDim.x + threadIdx.x;
    if (e >= E) return;
    int pos = atomicAdd(&cursor[erow[e]], 1);
    col_s[pos] = ecol[e];
}

// ---------------- init: g0 = fp16(dinv*x), acc = x ----------------
// One thread per float4 (4 features). row = i/32.
__global__ void init_g(const float4* __restrict__ vsrc,
                       const float4* __restrict__ dsrc,
                       const float* __restrict__ dinv,
                       __half2* __restrict__ g,
                       float4* __restrict__ acc,
                       long nv4, long total4) {
    long i = (long)blockIdx.x * blockDim.x + threadIdx.x;
    long stride = (long)gridDim.x * blockDim.x;
    for (; i < total4; i += stride) {
        float4 v = (i < nv4) ? vsrc[i] : dsrc[i - nv4];
        acc[i] = v;
        float w = dinv[i >> 5];               // 32 float4 per row
        __half2 h0 = __floats2half2_rn(w * v.x, w * v.y);
        __half2 h1 = __floats2half2_rn(w * v.z, w * v.w);
        g[i * 2] = h0;
        g[i * 2 + 1] = h1;
    }
}

// ---------------- gather SpMM (fp16 g): one wave per row ----------------
// s = sum_c g[c];  h_next = dinv[r]*s;  g_next = dinv[r]*h_next;
// acc = (acc + h_next) * scale
__global__ void spmm_csr_h(const int* __restrict__ row_ptr, const int* __restrict__ col_s,
                           const float* __restrict__ dinv, const __half2* __restrict__ g,
                           __half2* __restrict__ gnext, float2* __restrict__ acc,
                           float scale, int writeG, int N) {
    int gid = blockIdx.x * blockDim.x + threadIdx.x;
    int r = gid >> 6;
    if (r >= N) return;
    int lane = gid & 63;
    int start = row_ptr[r], end = row_ptr[r + 1];
    float sx = 0.0f, sy = 0.0f;
    int j = start;
    for (; j + 3 < end; j += 4) {
        int c0 = col_s[j], c1 = col_s[j + 1], c2 = col_s[j + 2], c3 = col_s[j + 3];
        float2 v0 = __half22float2(g[(long)c0 * 64 + lane]);
        float2 v1 = __half22float2(g[(long)c1 * 64 + lane]);
        float2 v2 = __half22float2(g[(long)c2 * 64 + lane]);
        float2 v3 = __half22float2(g[(long)c3 * 64 + lane]);
        sx += (v0.x + v1.x) + (v2.x + v3.x);
        sy += (v0.y + v1.y) + (v2.y + v3.y);
    }
    for (; j < end; ++j) {
        float2 v = __half22float2(g[(long)col_s[j] * 64 + lane]);
        sx += v.x;
        sy += v.y;
    }
    float dr = dinv[r];
    float hx = dr * sx, hy = dr * sy;
    long o = (long)r * 64 + lane;
    if (writeG) gnext[o] = __floats2half2_rn(dr * hx, dr * hy);
    float2 a = acc[o];
    a.x = (a.x + hx) * scale;
    a.y = (a.y + hy) * scale;
    acc[o] = a;
}

// ---------------- fallback (round-1 atomic path, fp32) ----------------
__global__ void init_copy(const float4* __restrict__ vsrc,
                          const float4* __restrict__ dsrc,
                          float4* __restrict__ h,
                          float4* __restrict__ acc,
                          long nv4, long total4) {
    long i = (long)blockIdx.x * blockDim.x + threadIdx.x;
    long stride = (long)gridDim.x * blockDim.x;
    for (; i < total4; i += stride) {
        float4 v = (i < nv4) ? vsrc[i] : dsrc[i - nv4];
        h[i] = v;
        acc[i] = v;
    }
}

__global__ void spmm_scatter(const int* __restrict__ erow, const int* __restrict__ ecol,
                             const float* __restrict__ eval, const float* __restrict__ h,
                             float* __restrict__ hnext, int E) {
    long tid = (long)blockIdx.x * blockDim.x + threadIdx.x;
    int e = (int)(tid >> 6);
    if (e >= E) return;
    int lane = (int)(tid & 63);
    int r = erow[e], c = ecol[e];
    float w = eval[e];
    const float2* src = reinterpret_cast<const float2*>(h + (long)c * D);
    float2 m = src[lane];
    float* dst = hnext + (long)r * D + lane * 2;
    atomicAdd(dst, w * m.x);
    atomicAdd(dst + 1, w * m.y);
}

__global__ void add_scale(float4* __restrict__ acc, const float4* __restrict__ b,
                          float s, long total4) {
    long i = (long)blockIdx.x * blockDim.x + threadIdx.x;
    long stride = (long)gridDim.x * blockDim.x;
    for (; i < total4; i += stride) {
        float4 a = acc[i];
        float4 v = b[i];
        a.x = (a.x + v.x) * s;
        a.y = (a.y + v.y) * s;
        a.z = (a.z + v.z) * s;
        a.w = (a.w + v.w) * s;
        acc[i] = a;
    }
}

extern "C" void kernel_launch(void* const* d_in, const int* in_sizes, int n_in,
                              void* d_out, int out_size, void* d_ws, size_t ws_size,
                              hipStream_t stream) {
    const int*   erow = (const int*)d_in[0];
    const int*   ecol = (const int*)d_in[1];
    const float* eval = (const float*)d_in[2];
    const float* vemb = (const float*)d_in[3];
    const float* demb = (const float*)d_in[4];

    int  E   = in_sizes[0];
    long nvD = in_sizes[3];
    long ndD = in_sizes[4];
    long ND  = nvD + ndD;
    int  N   = (int)(ND / D);

    float* out = (float*)d_out;

    // ws layout (fast path): two fp16 g buffers + CSR arrays
    char* w = (char*)d_ws;
    __half* gA = (__half*)w;  w += (size_t)ND * sizeof(__half);
    __half* gB = (__half*)w;  w += (size_t)ND * sizeof(__half);
    int* col_s    = (int*)w;  w += (size_t)E * sizeof(int);
    int* row_ptr  = (int*)w;  w += (size_t)(N + 1) * sizeof(int);
    int* cursor   = (int*)w;  w += (size_t)N * sizeof(int);
    int* deg      = (int*)w;  w += (size_t)N * sizeof(int);
    int* partials = (int*)w;  w += 1024 * sizeof(int);
    float* dinv   = (float*)w; w += (size_t)N * sizeof(float);
    size_t needed = (size_t)(w - (char*)d_ws);

    long total4 = ND / 4;
    long nv4    = nvD / 4;
    const int blk = 256;
    const int copyGrid = 2048;

    if (needed <= ws_size && N <= 1024 * 1024) {
        // ---------- CSR build ----------
        hipMemsetAsync(deg, 0, (size_t)N * sizeof(int), stream);
        int egrid = (E + blk - 1) / blk;
        hipLaunchKernelGGL(hist_deg, dim3(egrid), dim3(blk), 0, stream, erow, deg, E);

        int nb = (N + 1023) / 1024;
        hipLaunchKernelGGL(scan_block, dim3(nb), dim3(1024), 0, stream,
                           deg, row_ptr, partials, N);
        hipLaunchKernelGGL(scan_partials, dim3(1), dim3(1024), 0, stream, partials, nb);
        hipLaunchKernelGGL(finalize_rows, dim3(nb), dim3(1024), 0, stream,
                           deg, row_ptr, partials, cursor, dinv, N, E);
        hipLaunchKernelGGL(scatter_csr, dim3(egrid), dim3(blk), 0, stream,
                           erow, ecol, cursor, col_s, E);

        // ---------- init: g0 = fp16(dinv*x), acc = x ----------
        hipLaunchKernelGGL(init_g, dim3(copyGrid), dim3(blk), 0, stream,
                           (const float4*)vemb, (const float4*)demb, dinv,
                           (__half2*)gA, (float4*)out, nv4, total4);

        // ---------- 3 layers ----------
        __half* cur = gA;
        __half* nxt = gB;
        int rgrid = (N * 64 + blk - 1) / blk;
        for (int l = 0; l < 3; ++l) {
            float s = (l == 2) ? 0.25f : 1.0f;
            int writeG = (l < 2) ? 1 : 0;
            hipLaunchKernelGGL(spmm_csr_h, dim3(rgrid), dim3(blk), 0, stream,
                               row_ptr, col_s, dinv, (const __half2*)cur,
                               (__half2*)nxt, (float2*)out, s, writeG, N);
            __half* t = cur; cur = nxt; nxt = t;
        }
    } else {
        // ---------- fallback: atomic scatter path (fp32) ----------
        float* bufA = (float*)d_ws;
        float* bufB = bufA + ND;
        hipLaunchKernelGGL(init_copy, dim3(copyGrid), dim3(blk), 0, stream,
                           (const float4*)vemb, (const float4*)demb,
                           (float4*)bufA, (float4*)out, nv4, total4);
        float* cur = bufA;
        float* nxt = bufB;
        for (int l = 0; l < 3; ++l) {
            hipMemsetAsync(nxt, 0, (size_t)ND * sizeof(float), stream);
            long threads = (long)E * 64;
            int  sgrid   = (int)((threads + blk - 1) / blk);
            hipLaunchKernelGGL(spmm_scatter, dim3(sgrid), dim3(blk), 0, stream,
                               erow, ecol, eval, cur, nxt, E);
            float s = (l == 2) ? 0.25f : 1.0f;
            hipLaunchKernelGGL(add_scale, dim3(copyGrid), dim3(blk), 0, stream,
                               (float4*)out, (const float4*)nxt, s, total4);
            float* t = cur; cur = nxt; nxt = t;
        }
    }
}

// Round 4
// 349.721 us; speedup vs baseline: 11.4463x; 1.3164x over previous
//
#include <hip/hip_runtime.h>
#include <hip/hip_fp16.h>

static constexpr int D = 128;
static constexpr int RPB_LOG = 10;           // 1024 rows per bin
static constexpr int RPB = 1 << RPB_LOG;
static constexpr int MAX_BINS = 1024;        // supports N <= 1M rows
static constexpr int CHUNK = 8192;           // edges per binA block

// ---------------- CSR build ----------------
__global__ void hist_deg(const int* __restrict__ erow, int* __restrict__ deg, int E) {
    int e = blockIdx.x * blockDim.x + threadIdx.x;
    if (e < E) atomicAdd(&deg[erow[e]], 1);
}

__global__ void scan_block(const int* __restrict__ deg, int* __restrict__ excl_out,
                           int* __restrict__ partials, int N) {
    __shared__ int sm[1024];
    int t = threadIdx.x;
    int i = blockIdx.x * 1024 + t;
    int v = (i < N) ? deg[i] : 0;
    sm[t] = v;
    __syncthreads();
    for (int off = 1; off < 1024; off <<= 1) {
        int x = sm[t];
        int y = (t >= off) ? sm[t - off] : 0;
        __syncthreads();
        sm[t] = x + y;
        __syncthreads();
    }
    if (i < N) excl_out[i] = sm[t] - v;          // exclusive
    if (t == 1023) partials[blockIdx.x] = sm[1023];
}

__global__ void scan_partials(int* __restrict__ partials, int nb) {
    __shared__ int sm[1024];
    int t = threadIdx.x;
    int v = (t < nb) ? partials[t] : 0;
    sm[t] = v;
    __syncthreads();
    for (int off = 1; off < 1024; off <<= 1) {
        int x = sm[t];
        int y = (t >= off) ? sm[t - off] : 0;
        __syncthreads();
        sm[t] = x + y;
        __syncthreads();
    }
    if (t < nb) partials[t] = sm[t] - v;
}

// row_ptr += partials[block]; dinv = rsqrt(deg); gcur[bin] = row_ptr[bin*RPB]
__global__ void finalize_rows(const int* __restrict__ deg, int* __restrict__ row_ptr,
                              const int* __restrict__ partials, int* __restrict__ gcur,
                              float* __restrict__ dinv, int N, int E) {
    int i = blockIdx.x * 1024 + threadIdx.x;
    if (i < N) {
        int rp = row_ptr[i] + partials[blockIdx.x];
        row_ptr[i] = rp;
        if ((i & (RPB - 1)) == 0) gcur[i >> RPB_LOG] = rp;
        int dg = deg[i];
        dinv[i] = (dg > 0) ? rsqrtf((float)dg) : 0.0f;
    }
    if (i == 0 && blockIdx.x == 0) row_ptr[N] = E;
}

// Pass A: bin edges into per-bin slices of tmp (pairs), dense writes.
__global__ void binA(const int* __restrict__ erow, const int* __restrict__ ecol,
                     int* __restrict__ gcur, int2* __restrict__ tmp, int E, int nbins) {
    __shared__ int hist[MAX_BINS];
    __shared__ int base[MAX_BINS];
    __shared__ int lcur[MAX_BINS];
    int t = threadIdx.x;                       // 256 threads
    int e0 = blockIdx.x * CHUNK;
    for (int i = t; i < MAX_BINS; i += 256) { hist[i] = 0; lcur[i] = 0; }
    __syncthreads();
    // step 1: local histogram
    for (int k = 0; k < CHUNK / 256; ++k) {
        int e = e0 + t + k * 256;
        if (e < E) atomicAdd(&hist[erow[e] >> RPB_LOG], 1);
    }
    __syncthreads();
    // step 2: reserve global space per bin
    for (int b = t; b < nbins; b += 256)
        base[b] = hist[b] ? atomicAdd(&gcur[b], hist[b]) : 0;
    __syncthreads();
    // step 3: scatter pairs into reserved slices (L2-hot re-read of edges)
    for (int k = 0; k < CHUNK / 256; ++k) {
        int e = e0 + t + k * 256;
        if (e < E) {
            int r = erow[e];
            int b = r >> RPB_LOG;
            int pos = base[b] + atomicAdd(&lcur[b], 1);
            tmp[pos] = make_int2(r, ecol[e]);
        }
    }
}

// Pass B: one block per bin; order pairs into final col_s via LDS cursors.
__global__ void binB(const int2* __restrict__ tmp, const int* __restrict__ row_ptr,
                     int* __restrict__ col_s, int N) {
    __shared__ int cur[RPB];
    int b = blockIdx.x;
    int r0 = b << RPB_LOG;
    int t = threadIdx.x;                       // 1024 threads
    int r = r0 + t;
    cur[t] = (r < N) ? row_ptr[r] : 0;
    __syncthreads();
    int r1 = (r0 + RPB < N) ? (r0 + RPB) : N;
    int start = row_ptr[r0];
    int end = row_ptr[r1];
    for (int p = start + t; p < end; p += 1024) {
        int2 pr = tmp[p];
        int pos = atomicAdd(&cur[pr.x - r0], 1);
        col_s[pos] = pr.y;
    }
}

// ---------------- init: g0 = fp16(dinv*x), acc = x ----------------
__global__ void init_g(const float4* __restrict__ vsrc,
                       const float4* __restrict__ dsrc,
                       const float* __restrict__ dinv,
                       __half2* __restrict__ g,
                       float4* __restrict__ acc,
                       long nv4, long total4) {
    long i = (long)blockIdx.x * blockDim.x + threadIdx.x;
    long stride = (long)gridDim.x * blockDim.x;
    for (; i < total4; i += stride) {
        float4 v = (i < nv4) ? vsrc[i] : dsrc[i - nv4];
        acc[i] = v;
        float w = dinv[i >> 5];               // 32 float4 per row
        __half2 h0 = __floats2half2_rn(w * v.x, w * v.y);
        __half2 h1 = __floats2half2_rn(w * v.z, w * v.w);
        g[i * 2] = h0;
        g[i * 2 + 1] = h1;
    }
}

// ---------------- gather SpMM (fp16 g): one wave per row ----------------
__global__ void spmm_csr_h(const int* __restrict__ row_ptr, const int* __restrict__ col_s,
                           const float* __restrict__ dinv, const __half2* __restrict__ g,
                           __half2* __restrict__ gnext, float2* __restrict__ acc,
                           float scale, int writeG, int N) {
    int gid = blockIdx.x * blockDim.x + threadIdx.x;
    int r = __builtin_amdgcn_readfirstlane(gid >> 6);   // wave-uniform row -> SGPR
    if (r >= N) return;
    int lane = gid & 63;
    int start = row_ptr[r], end = row_ptr[r + 1];
    float sx = 0.0f, sy = 0.0f;
    int j = start;
    for (; j + 3 < end; j += 4) {
        int c0 = col_s[j], c1 = col_s[j + 1], c2 = col_s[j + 2], c3 = col_s[j + 3];
        float2 v0 = __half22float2(g[(long)c0 * 64 + lane]);
        float2 v1 = __half22float2(g[(long)c1 * 64 + lane]);
        float2 v2 = __half22float2(g[(long)c2 * 64 + lane]);
        float2 v3 = __half22float2(g[(long)c3 * 64 + lane]);
        sx += (v0.x + v1.x) + (v2.x + v3.x);
        sy += (v0.y + v1.y) + (v2.y + v3.y);
    }
    for (; j < end; ++j) {
        float2 v = __half22float2(g[(long)col_s[j] * 64 + lane]);
        sx += v.x;
        sy += v.y;
    }
    float dr = dinv[r];
    float hx = dr * sx, hy = dr * sy;
    long o = (long)r * 64 + lane;
    if (writeG) gnext[o] = __floats2half2_rn(dr * hx, dr * hy);
    float2 a = acc[o];
    a.x = (a.x + hx) * scale;
    a.y = (a.y + hy) * scale;
    acc[o] = a;
}

// ---------------- fallback (atomic scatter path, fp32) ----------------
__global__ void init_copy(const float4* __restrict__ vsrc,
                          const float4* __restrict__ dsrc,
                          float4* __restrict__ h,
                          float4* __restrict__ acc,
                          long nv4, long total4) {
    long i = (long)blockIdx.x * blockDim.x + threadIdx.x;
    long stride = (long)gridDim.x * blockDim.x;
    for (; i < total4; i += stride) {
        float4 v = (i < nv4) ? vsrc[i] : dsrc[i - nv4];
        h[i] = v;
        acc[i] = v;
    }
}

__global__ void spmm_scatter(const int* __restrict__ erow, const int* __restrict__ ecol,
                             const float* __restrict__ eval, const float* __restrict__ h,
                             float* __restrict__ hnext, int E) {
    long tid = (long)blockIdx.x * blockDim.x + threadIdx.x;
    int e = (int)(tid >> 6);
    if (e >= E) return;
    int lane = (int)(tid & 63);
    int r = erow[e], c = ecol[e];
    float w = eval[e];
    const float2* src = reinterpret_cast<const float2*>(h + (long)c * D);
    float2 m = src[lane];
    float* dst = hnext + (long)r * D + lane * 2;
    atomicAdd(dst, w * m.x);
    atomicAdd(dst + 1, w * m.y);
}

__global__ void add_scale(float4* __restrict__ acc, const float4* __restrict__ b,
                          float s, long total4) {
    long i = (long)blockIdx.x * blockDim.x + threadIdx.x;
    long stride = (long)gridDim.x * blockDim.x;
    for (; i < total4; i += stride) {
        float4 a = acc[i];
        float4 v = b[i];
        a.x = (a.x + v.x) * s;
        a.y = (a.y + v.y) * s;
        a.z = (a.z + v.z) * s;
        a.w = (a.w + v.w) * s;
        acc[i] = a;
    }
}

extern "C" void kernel_launch(void* const* d_in, const int* in_sizes, int n_in,
                              void* d_out, int out_size, void* d_ws, size_t ws_size,
                              hipStream_t stream) {
    const int*   erow = (const int*)d_in[0];
    const int*   ecol = (const int*)d_in[1];
    const float* eval = (const float*)d_in[2];
    const float* vemb = (const float*)d_in[3];
    const float* demb = (const float*)d_in[4];

    int  E   = in_sizes[0];
    long nvD = in_sizes[3];
    long ndD = in_sizes[4];
    long ND  = nvD + ndD;
    int  N   = (int)(ND / D);
    int  nbins = (N + RPB - 1) >> RPB_LOG;

    float* out = (float*)d_out;

    // ws layout (fast path)
    char* w = (char*)d_ws;
    __half* gA = (__half*)w;  w += (size_t)ND * sizeof(__half);
    __half* gB = (__half*)w;  w += (size_t)ND * sizeof(__half);
    int* col_s    = (int*)w;  w += (size_t)E * sizeof(int);
    int2* tmp     = (int2*)w; w += (size_t)E * sizeof(int2);
    int* row_ptr  = (int*)w;  w += (size_t)(N + 1) * sizeof(int);
    int* deg      = (int*)w;  w += (size_t)N * sizeof(int);
    int* partials = (int*)w;  w += 1024 * sizeof(int);
    int* gcur     = (int*)w;  w += MAX_BINS * sizeof(int);
    float* dinv   = (float*)w; w += (size_t)N * sizeof(float);
    size_t needed = (size_t)(w - (char*)d_ws);

    long total4 = ND / 4;
    long nv4    = nvD / 4;
    const int blk = 256;
    const int copyGrid = 2048;

    if (needed <= ws_size && nbins <= MAX_BINS) {
        // ---------- CSR build ----------
        hipMemsetAsync(deg, 0, (size_t)N * sizeof(int), stream);
        int egrid = (E + blk - 1) / blk;
        hipLaunchKernelGGL(hist_deg, dim3(egrid), dim3(blk), 0, stream, erow, deg, E);

        int nb = (N + 1023) / 1024;
        hipLaunchKernelGGL(scan_block, dim3(nb), dim3(1024), 0, stream,
                           deg, row_ptr, partials, N);
        hipLaunchKernelGGL(scan_partials, dim3(1), dim3(1024), 0, stream, partials, nb);
        hipLaunchKernelGGL(finalize_rows, dim3(nb), dim3(1024), 0, stream,
                           deg, row_ptr, partials, gcur, dinv, N, E);

        int nblkA = (E + CHUNK - 1) / CHUNK;
        hipLaunchKernelGGL(binA, dim3(nblkA), dim3(256), 0, stream,
                           erow, ecol, gcur, tmp, E, nbins);
        hipLaunchKernelGGL(binB, dim3(nbins), dim3(1024), 0, stream,
                           tmp, row_ptr, col_s, N);

        // ---------- init: g0 = fp16(dinv*x), acc = x ----------
        hipLaunchKernelGGL(init_g, dim3(copyGrid), dim3(blk), 0, stream,
                           (const float4*)vemb, (const float4*)demb, dinv,
                           (__half2*)gA, (float4*)out, nv4, total4);

        // ---------- 3 layers ----------
        __half* cur = gA;
        __half* nxt = gB;
        int rgrid = (int)(((long)N * 64 + blk - 1) / blk);
        for (int l = 0; l < 3; ++l) {
            float s = (l == 2) ? 0.25f : 1.0f;
            int writeG = (l < 2) ? 1 : 0;
            hipLaunchKernelGGL(spmm_csr_h, dim3(rgrid), dim3(blk), 0, stream,
                               row_ptr, col_s, dinv, (const __half2*)cur,
                               (__half2*)nxt, (float2*)out, s, writeG, N);
            __half* t = cur; cur = nxt; nxt = t;
        }
    } else {
        // ---------- fallback: atomic scatter path (fp32) ----------
        float* bufA = (float*)d_ws;
        float* bufB = bufA + ND;
        hipLaunchKernelGGL(init_copy, dim3(copyGrid), dim3(blk), 0, stream,
                           (const float4*)vemb, (const float4*)demb,
                           (float4*)bufA, (float4*)out, nv4, total4);
        float* cur = bufA;
        float* nxt = bufB;
        for (int l = 0; l < 3; ++l) {
            hipMemsetAsync(nxt, 0, (size_t)ND * sizeof(float), stream);
            long threads = (long)E * 64;
            int  sgrid   = (int)((threads + blk - 1) / blk);
            hipLaunchKernelGGL(spmm_scatter, dim3(sgrid), dim3(blk), 0, stream,
                               erow, ecol, eval, cur, nxt, E);
            float s = (l == 2) ? 0.25f : 1.0f;
            hipLaunchKernelGGL(add_scale, dim3(copyGrid), dim3(blk), 0, stream,
                               (float4*)out, (const float4*)nxt, s, total4);
            float* t = cur; cur = nxt; nxt = t;
        }
    }
}

// Round 5
// 286.577 us; speedup vs baseline: 13.9684x; 1.2203x over previous
//
#include <hip/hip_runtime.h>
#include <hip/hip_fp16.h>

static constexpr int D = 128;
static constexpr int RPB_LOG = 10;           // 1024 rows per bin
static constexpr int RPB = 1 << RPB_LOG;
static constexpr int MAX_BINS = 1024;        // supports N <= 1M rows
static constexpr int CHUNK = 8192;           // edges per binA/binCount block

// ---------------- pass 0: count edges per bin ----------------
__global__ void binCount(const int* __restrict__ erow, int* __restrict__ bin_cnt,
                         int E, int nbins) {
    __shared__ int hist[MAX_BINS];
    int t = threadIdx.x;                       // 256
    int e0 = blockIdx.x * CHUNK;
    for (int i = t; i < nbins; i += 256) hist[i] = 0;
    __syncthreads();
    for (int k = 0; k < CHUNK / 256; ++k) {
        int e = e0 + t + k * 256;
        if (e < E) atomicAdd(&hist[erow[e] >> RPB_LOG], 1);
    }
    __syncthreads();
    for (int b = t; b < nbins; b += 256)
        if (hist[b]) atomicAdd(&bin_cnt[b], hist[b]);
}

// ---------------- pass 0b: exclusive scan of bin counts ----------------
__global__ void scanBins(const int* __restrict__ bin_cnt, int* __restrict__ bin_base,
                         int* __restrict__ gcur, int nbins, int E) {
    __shared__ int sm[MAX_BINS];
    int t = threadIdx.x;                       // 1024
    int v = (t < nbins) ? bin_cnt[t] : 0;
    sm[t] = v;
    __syncthreads();
    for (int off = 1; off < MAX_BINS; off <<= 1) {
        int x = sm[t];
        int y = (t >= off) ? sm[t - off] : 0;
        __syncthreads();
        sm[t] = x + y;
        __syncthreads();
    }
    if (t < nbins) {
        int excl = sm[t] - v;
        bin_base[t] = excl;
        gcur[t] = excl;
    }
    if (t == 0) bin_base[nbins] = E;
}

// ---------------- pass A: scatter (row,col) pairs into bin slices ----------------
__global__ void binA(const int* __restrict__ erow, const int* __restrict__ ecol,
                     int* __restrict__ gcur, int2* __restrict__ tmp, int E, int nbins) {
    __shared__ int hist[MAX_BINS];
    __shared__ int base[MAX_BINS];
    __shared__ int lcur[MAX_BINS];
    int t = threadIdx.x;                       // 256
    int e0 = blockIdx.x * CHUNK;
    for (int i = t; i < nbins; i += 256) { hist[i] = 0; lcur[i] = 0; }
    __syncthreads();
    for (int k = 0; k < CHUNK / 256; ++k) {
        int e = e0 + t + k * 256;
        if (e < E) atomicAdd(&hist[erow[e] >> RPB_LOG], 1);
    }
    __syncthreads();
    for (int b = t; b < nbins; b += 256)
        base[b] = hist[b] ? atomicAdd(&gcur[b], hist[b]) : 0;
    __syncthreads();
    for (int k = 0; k < CHUNK / 256; ++k) {
        int e = e0 + t + k * 256;
        if (e < E) {
            int r = erow[e];
            int b = r >> RPB_LOG;
            int pos = base[b] + atomicAdd(&lcur[b], 1);
            tmp[pos] = make_int2(r, ecol[e]);
        }
    }
}

// ---------------- pass B: per-bin degree hist + scan + order ----------------
// Produces row_ptr, dinv, and ordered col_s — no global scans needed.
__global__ void binB(const int2* __restrict__ tmp, const int* __restrict__ bin_base,
                     int* __restrict__ row_ptr, float* __restrict__ dinv,
                     int* __restrict__ col_s, int N, int E, int nbins) {
    __shared__ int cnt[RPB];
    __shared__ int sm[RPB];
    __shared__ int cur[RPB];
    int b = blockIdx.x;
    int r0 = b << RPB_LOG;
    int t = threadIdx.x;                       // 1024
    cnt[t] = 0;
    __syncthreads();
    int start = bin_base[b];
    int end = bin_base[b + 1];
    for (int p = start + t; p < end; p += RPB)
        atomicAdd(&cnt[tmp[p].x - r0], 1);
    __syncthreads();
    int v = cnt[t];
    sm[t] = v;
    __syncthreads();
    for (int off = 1; off < RPB; off <<= 1) {
        int x = sm[t];
        int y = (t >= off) ? sm[t - off] : 0;
        __syncthreads();
        sm[t] = x + y;
        __syncthreads();
    }
    int rp = start + sm[t] - v;                // global exclusive position
    int r = r0 + t;
    if (r < N) {
        row_ptr[r] = rp;
        dinv[r] = (v > 0) ? rsqrtf((float)v) : 0.0f;
    }
    if (b == 0 && t == 0) row_ptr[N] = E;
    cur[t] = rp;
    __syncthreads();
    for (int p = start + t; p < end; p += RPB) {
        int2 pr = tmp[p];
        int pos = atomicAdd(&cur[pr.x - r0], 1);
        col_s[pos] = pr.y;
    }
}

// ---------------- init: g0 = fp16(dinv*x) ----------------
__global__ void init_g(const float4* __restrict__ vsrc,
                       const float4* __restrict__ dsrc,
                       const float* __restrict__ dinv,
                       __half2* __restrict__ g,
                       long nv4, long total4) {
    long i = (long)blockIdx.x * blockDim.x + threadIdx.x;
    long stride = (long)gridDim.x * blockDim.x;
    for (; i < total4; i += stride) {
        float4 v = (i < nv4) ? vsrc[i] : dsrc[i - nv4];
        float w = dinv[i >> 5];               // 32 float4 per row
        g[i * 2]     = __floats2half2_rn(w * v.x, w * v.y);
        g[i * 2 + 1] = __floats2half2_rn(w * v.z, w * v.w);
    }
}

// ---------------- gather SpMM (fp16 g): one wave per row ----------------
// s = sum_c g[c];  h_next = dinv[r]*s;  acc = (accIn + h_next)*scale
// layer 1: accIn = x read from xv/xd (nvRows>=0); else accIn = acc[o].
__global__ void spmm_csr_h(const int* __restrict__ row_ptr, const int* __restrict__ col_s,
                           const float* __restrict__ dinv, const __half2* __restrict__ g,
                           __half2* __restrict__ gnext, float2* __restrict__ acc,
                           const float2* __restrict__ xv, const float2* __restrict__ xd,
                           int nvRows, float scale, int writeG, int N) {
    int gid = blockIdx.x * blockDim.x + threadIdx.x;
    int r = __builtin_amdgcn_readfirstlane(gid >> 6);   // wave-uniform row -> SGPR
    if (r >= N) return;
    int lane = gid & 63;
    int start = row_ptr[r], end = row_ptr[r + 1];
    float sx = 0.0f, sy = 0.0f;
    int j = start;
    for (; j + 3 < end; j += 4) {
        int c0 = col_s[j], c1 = col_s[j + 1], c2 = col_s[j + 2], c3 = col_s[j + 3];
        float2 v0 = __half22float2(g[(long)c0 * 64 + lane]);
        float2 v1 = __half22float2(g[(long)c1 * 64 + lane]);
        float2 v2 = __half22float2(g[(long)c2 * 64 + lane]);
        float2 v3 = __half22float2(g[(long)c3 * 64 + lane]);
        sx += (v0.x + v1.x) + (v2.x + v3.x);
        sy += (v0.y + v1.y) + (v2.y + v3.y);
    }
    for (; j < end; ++j) {
        float2 v = __half22float2(g[(long)col_s[j] * 64 + lane]);
        sx += v.x;
        sy += v.y;
    }
    float dr = dinv[r];
    float hx = dr * sx, hy = dr * sy;
    long o = (long)r * 64 + lane;
    if (writeG) gnext[o] = __floats2half2_rn(dr * hx, dr * hy);
    float2 a;
    if (nvRows >= 0) {
        const float2* asrc = (r < nvRows) ? (xv + (long)r * 64)
                                          : (xd + (long)(r - nvRows) * 64);
        a = asrc[lane];
    } else {
        a = acc[o];
    }
    a.x = (a.x + hx) * scale;
    a.y = (a.y + hy) * scale;
    acc[o] = a;
}

// ---------------- fallback (atomic scatter path, fp32) ----------------
__global__ void init_copy(const float4* __restrict__ vsrc,
                          const float4* __restrict__ dsrc,
                          float4* __restrict__ h,
                          float4* __restrict__ acc,
                          long nv4, long total4) {
    long i = (long)blockIdx.x * blockDim.x + threadIdx.x;
    long stride = (long)gridDim.x * blockDim.x;
    for (; i < total4; i += stride) {
        float4 v = (i < nv4) ? vsrc[i] : dsrc[i - nv4];
        h[i] = v;
        acc[i] = v;
    }
}

__global__ void spmm_scatter(const int* __restrict__ erow, const int* __restrict__ ecol,
                             const float* __restrict__ eval, const float* __restrict__ h,
                             float* __restrict__ hnext, int E) {
    long tid = (long)blockIdx.x * blockDim.x + threadIdx.x;
    int e = (int)(tid >> 6);
    if (e >= E) return;
    int lane = (int)(tid & 63);
    int r = erow[e], c = ecol[e];
    float w = eval[e];
    const float2* src = reinterpret_cast<const float2*>(h + (long)c * D);
    float2 m = src[lane];
    float* dst = hnext + (long)r * D + lane * 2;
    atomicAdd(dst, w * m.x);
    atomicAdd(dst + 1, w * m.y);
}

__global__ void add_scale(float4* __restrict__ acc, const float4* __restrict__ b,
                          float s, long total4) {
    long i = (long)blockIdx.x * blockDim.x + threadIdx.x;
    long stride = (long)gridDim.x * blockDim.x;
    for (; i < total4; i += stride) {
        float4 a = acc[i];
        float4 v = b[i];
        a.x = (a.x + v.x) * s;
        a.y = (a.y + v.y) * s;
        a.z = (a.z + v.z) * s;
        a.w = (a.w + v.w) * s;
        acc[i] = a;
    }
}

extern "C" void kernel_launch(void* const* d_in, const int* in_sizes, int n_in,
                              void* d_out, int out_size, void* d_ws, size_t ws_size,
                              hipStream_t stream) {
    const int*   erow = (const int*)d_in[0];
    const int*   ecol = (const int*)d_in[1];
    const float* eval = (const float*)d_in[2];
    const float* vemb = (const float*)d_in[3];
    const float* demb = (const float*)d_in[4];

    int  E   = in_sizes[0];
    long nvD = in_sizes[3];
    long ndD = in_sizes[4];
    long ND  = nvD + ndD;
    int  N   = (int)(ND / D);
    int  nvRows = (int)(nvD / D);
    int  nbins = (N + RPB - 1) >> RPB_LOG;

    float* out = (float*)d_out;

    // ws layout (fast path)
    char* w = (char*)d_ws;
    __half* gA = (__half*)w;  w += (size_t)ND * sizeof(__half);
    __half* gB = (__half*)w;  w += (size_t)ND * sizeof(__half);
    int* col_s    = (int*)w;  w += (size_t)E * sizeof(int);
    int2* tmp     = (int2*)w; w += (size_t)E * sizeof(int2);
    int* row_ptr  = (int*)w;  w += (size_t)(N + 1) * sizeof(int);
    int* bin_cnt  = (int*)w;  w += MAX_BINS * sizeof(int);
    int* bin_base = (int*)w;  w += (MAX_BINS + 1) * sizeof(int);
    int* gcur     = (int*)w;  w += MAX_BINS * sizeof(int);
    float* dinv   = (float*)w; w += (size_t)N * sizeof(float);
    size_t needed = (size_t)(w - (char*)d_ws);

    long total4 = ND / 4;
    long nv4    = nvD / 4;
    const int blk = 256;
    const int copyGrid = 2048;

    if (needed <= ws_size && nbins <= MAX_BINS) {
        // ---------- CSR build (bin-local, no global row scans) ----------
        hipMemsetAsync(bin_cnt, 0, MAX_BINS * sizeof(int), stream);
        int nblkA = (E + CHUNK - 1) / CHUNK;
        hipLaunchKernelGGL(binCount, dim3(nblkA), dim3(256), 0, stream,
                           erow, bin_cnt, E, nbins);
        hipLaunchKernelGGL(scanBins, dim3(1), dim3(1024), 0, stream,
                           bin_cnt, bin_base, gcur, nbins, E);
        hipLaunchKernelGGL(binA, dim3(nblkA), dim3(256), 0, stream,
                           erow, ecol, gcur, tmp, E, nbins);
        hipLaunchKernelGGL(binB, dim3(nbins), dim3(RPB), 0, stream,
                           tmp, bin_base, row_ptr, dinv, col_s, N, E, nbins);

        // ---------- init: g0 = fp16(dinv*x) ----------
        hipLaunchKernelGGL(init_g, dim3(copyGrid), dim3(blk), 0, stream,
                           (const float4*)vemb, (const float4*)demb, dinv,
                           (__half2*)gA, nv4, total4);

        // ---------- 3 layers ----------
        __half* cur = gA;
        __half* nxt = gB;
        int rgrid = (int)(((long)N * 64 + blk - 1) / blk);
        for (int l = 0; l < 3; ++l) {
            float s = (l == 2) ? 0.25f : 1.0f;
            int writeG = (l < 2) ? 1 : 0;
            int nvArg = (l == 0) ? nvRows : -1;
            hipLaunchKernelGGL(spmm_csr_h, dim3(rgrid), dim3(blk), 0, stream,
                               row_ptr, col_s, dinv, (const __half2*)cur,
                               (__half2*)nxt, (float2*)out,
                               (const float2*)vemb, (const float2*)demb,
                               nvArg, s, writeG, N);
            __half* t = cur; cur = nxt; nxt = t;
        }
    } else {
        // ---------- fallback: atomic scatter path (fp32) ----------
        float* bufA = (float*)d_ws;
        float* bufB = bufA + ND;
        hipLaunchKernelGGL(init_copy, dim3(copyGrid), dim3(blk), 0, stream,
                           (const float4*)vemb, (const float4*)demb,
                           (float4*)bufA, (float4*)out, nv4, total4);
        float* cur = bufA;
        float* nxt = bufB;
        for (int l = 0; l < 3; ++l) {
            hipMemsetAsync(nxt, 0, (size_t)ND * sizeof(float), stream);
            long threads = (long)E * 64;
            int  sgrid   = (int)((threads + blk - 1) / blk);
            hipLaunchKernelGGL(spmm_scatter, dim3(sgrid), dim3(blk), 0, stream,
                               erow, ecol, eval, cur, nxt, E);
            float s = (l == 2) ? 0.25f : 1.0f;
            hipLaunchKernelGGL(add_scale, dim3(copyGrid), dim3(blk), 0, stream,
                               (float4*)out, (const float4*)nxt, s, total4);
            float* t = cur; cur = nxt; nxt = t;
        }
    }
}

// Round 6
// 265.983 us; speedup vs baseline: 15.0499x; 1.0774x over previous
//
#include <hip/hip_runtime.h>
#include <hip/hip_fp16.h>

static constexpr int D = 128;
static constexpr int RPB_LOG = 10;           // 1024 rows per bin
static constexpr int RPB = 1 << RPB_LOG;
static constexpr int MAX_BINS = 1024;        // supports N <= 1M rows
static constexpr int CHUNK = 8192;           // edges per binA/binCount block

// ---------------- pass 0: count edges per bin ----------------
__global__ void binCount(const int* __restrict__ erow, int* __restrict__ bin_cnt,
                         int E, int nbins) {
    __shared__ int hist[MAX_BINS];
    int t = threadIdx.x;                       // 256
    int e0 = blockIdx.x * CHUNK;
    for (int i = t; i < nbins; i += 256) hist[i] = 0;
    __syncthreads();
    for (int k = 0; k < CHUNK / 256; ++k) {
        int e = e0 + t + k * 256;
        if (e < E) atomicAdd(&hist[erow[e] >> RPB_LOG], 1);
    }
    __syncthreads();
    for (int b = t; b < nbins; b += 256)
        if (hist[b]) atomicAdd(&bin_cnt[b], hist[b]);
}

// ---------------- pass 0b: exclusive scan of bin counts ----------------
__global__ void scanBins(const int* __restrict__ bin_cnt, int* __restrict__ bin_base,
                         int* __restrict__ gcur, int nbins, int E) {
    __shared__ int sm[MAX_BINS];
    int t = threadIdx.x;                       // 1024
    int v = (t < nbins) ? bin_cnt[t] : 0;
    sm[t] = v;
    __syncthreads();
    for (int off = 1; off < MAX_BINS; off <<= 1) {
        int x = sm[t];
        int y = (t >= off) ? sm[t - off] : 0;
        __syncthreads();
        sm[t] = x + y;
        __syncthreads();
    }
    if (t < nbins) {
        int excl = sm[t] - v;
        bin_base[t] = excl;
        gcur[t] = excl;
    }
    if (t == 0) bin_base[nbins] = E;
}

// ---------------- pass A: scatter (row,col) pairs into bin slices ----------------
__global__ void binA(const int* __restrict__ erow, const int* __restrict__ ecol,
                     int* __restrict__ gcur, int2* __restrict__ tmp, int E, int nbins) {
    __shared__ int hist[MAX_BINS];
    __shared__ int base[MAX_BINS];
    __shared__ int lcur[MAX_BINS];
    int t = threadIdx.x;                       // 256
    int e0 = blockIdx.x * CHUNK;
    for (int i = t; i < nbins; i += 256) { hist[i] = 0; lcur[i] = 0; }
    __syncthreads();
    for (int k = 0; k < CHUNK / 256; ++k) {
        int e = e0 + t + k * 256;
        if (e < E) atomicAdd(&hist[erow[e] >> RPB_LOG], 1);
    }
    __syncthreads();
    for (int b = t; b < nbins; b += 256)
        base[b] = hist[b] ? atomicAdd(&gcur[b], hist[b]) : 0;
    __syncthreads();
    for (int k = 0; k < CHUNK / 256; ++k) {
        int e = e0 + t + k * 256;
        if (e < E) {
            int r = erow[e];
            int b = r >> RPB_LOG;
            int pos = base[b] + atomicAdd(&lcur[b], 1);
            tmp[pos] = make_int2(r, ecol[e]);
        }
    }
}

// ---------------- pass B: per-bin degree hist + scan + order ----------------
// Produces row_ptr, dinv (rsqrt deg), rdinv (sqrt deg), ordered col_s.
__global__ void binB(const int2* __restrict__ tmp, const int* __restrict__ bin_base,
                     int* __restrict__ row_ptr, float* __restrict__ dinv,
                     float* __restrict__ rdinv, int* __restrict__ col_s,
                     int N, int E, int nbins) {
    __shared__ int cnt[RPB];
    __shared__ int sm[RPB];
    __shared__ int cur[RPB];
    int b = blockIdx.x;
    int r0 = b << RPB_LOG;
    int t = threadIdx.x;                       // 1024
    cnt[t] = 0;
    __syncthreads();
    int start = bin_base[b];
    int end = bin_base[b + 1];
    for (int p = start + t; p < end; p += RPB)
        atomicAdd(&cnt[tmp[p].x - r0], 1);
    __syncthreads();
    int v = cnt[t];
    sm[t] = v;
    __syncthreads();
    for (int off = 1; off < RPB; off <<= 1) {
        int x = sm[t];
        int y = (t >= off) ? sm[t - off] : 0;
        __syncthreads();
        sm[t] = x + y;
        __syncthreads();
    }
    int rp = start + sm[t] - v;                // global exclusive position
    int r = r0 + t;
    if (r < N) {
        row_ptr[r] = rp;
        dinv[r]  = (v > 0) ? rsqrtf((float)v) : 0.0f;
        rdinv[r] = (v > 0) ? sqrtf((float)v) : 0.0f;
    }
    if (b == 0 && t == 0) row_ptr[N] = E;
    cur[t] = rp;
    __syncthreads();
    for (int p = start + t; p < end; p += RPB) {
        int2 pr = tmp[p];
        int pos = atomicAdd(&cur[pr.x - r0], 1);
        col_s[pos] = pr.y;
    }
}

// ---------------- init: g0 = fp16(dinv*x) ----------------
__global__ void init_g(const float4* __restrict__ vsrc,
                       const float4* __restrict__ dsrc,
                       const float* __restrict__ dinv,
                       __half2* __restrict__ g,
                       long nv4, long total4) {
    long i = (long)blockIdx.x * blockDim.x + threadIdx.x;
    long stride = (long)gridDim.x * blockDim.x;
    for (; i < total4; i += stride) {
        float4 v = (i < nv4) ? vsrc[i] : dsrc[i - nv4];
        float w = dinv[i >> 5];               // 32 float4 per row
        g[i * 2]     = __floats2half2_rn(w * v.x, w * v.y);
        g[i * 2 + 1] = __floats2half2_rn(w * v.z, w * v.w);
    }
}

// ---------------- mid layers: gnext = fp16(dinv^2 * sum_c g[c]) ----------------
__global__ void spmm_mid(const int* __restrict__ row_ptr, const int* __restrict__ col_s,
                         const float* __restrict__ dinv, const __half2* __restrict__ g,
                         __half2* __restrict__ gnext, int N) {
    int gid = blockIdx.x * blockDim.x + threadIdx.x;
    int r = __builtin_amdgcn_readfirstlane(gid >> 6);   // wave-uniform row -> SGPR
    if (r >= N) return;
    int lane = gid & 63;
    int start = row_ptr[r], end = row_ptr[r + 1];
    float sx = 0.0f, sy = 0.0f;
    int j = start;
    for (; j + 3 < end; j += 4) {
        int c0 = col_s[j], c1 = col_s[j + 1], c2 = col_s[j + 2], c3 = col_s[j + 3];
        float2 v0 = __half22float2(g[(long)c0 * 64 + lane]);
        float2 v1 = __half22float2(g[(long)c1 * 64 + lane]);
        float2 v2 = __half22float2(g[(long)c2 * 64 + lane]);
        float2 v3 = __half22float2(g[(long)c3 * 64 + lane]);
        sx += (v0.x + v1.x) + (v2.x + v3.x);
        sy += (v0.y + v1.y) + (v2.y + v3.y);
    }
    for (; j < end; ++j) {
        float2 v = __half22float2(g[(long)col_s[j] * 64 + lane]);
        sx += v.x;
        sy += v.y;
    }
    float dr = dinv[r];
    float d2 = dr * dr;
    long o = (long)r * 64 + lane;
    gnext[o] = __floats2half2_rn(d2 * sx, d2 * sy);
}

// ---------------- final layer: out = 0.25*(x + (g1+g2)*rdinv + dinv*sum g2[c]) --
__global__ void spmm_final(const int* __restrict__ row_ptr, const int* __restrict__ col_s,
                           const float* __restrict__ dinv, const float* __restrict__ rdinv,
                           const __half2* __restrict__ g,     // g2 (gather source)
                           const __half2* __restrict__ g1,    // layer-1 output
                           const float2* __restrict__ xv, const float2* __restrict__ xd,
                           int nvRows, float2* __restrict__ out, int N) {
    int gid = blockIdx.x * blockDim.x + threadIdx.x;
    int r = __builtin_amdgcn_readfirstlane(gid >> 6);
    if (r >= N) return;
    int lane = gid & 63;
    int start = row_ptr[r], end = row_ptr[r + 1];
    float sx = 0.0f, sy = 0.0f;
    int j = start;
    for (; j + 3 < end; j += 4) {
        int c0 = col_s[j], c1 = col_s[j + 1], c2 = col_s[j + 2], c3 = col_s[j + 3];
        float2 v0 = __half22float2(g[(long)c0 * 64 + lane]);
        float2 v1 = __half22float2(g[(long)c1 * 64 + lane]);
        float2 v2 = __half22float2(g[(long)c2 * 64 + lane]);
        float2 v3 = __half22float2(g[(long)c3 * 64 + lane]);
        sx += (v0.x + v1.x) + (v2.x + v3.x);
        sy += (v0.y + v1.y) + (v2.y + v3.y);
    }
    for (; j < end; ++j) {
        float2 v = __half22float2(g[(long)col_s[j] * 64 + lane]);
        sx += v.x;
        sy += v.y;
    }
    float dr = dinv[r];
    float h3x = dr * sx, h3y = dr * sy;
    long o = (long)r * 64 + lane;
    float rd = rdinv[r];
    float2 a = (r < nvRows) ? xv[(long)r * 64 + lane]
                            : xd[(long)(r - nvRows) * 64 + lane];
    float2 p1 = __half22float2(g1[o]);
    float2 p2 = __half22float2(g[o]);
    float ox = 0.25f * (a.x + (p1.x + p2.x) * rd + h3x);
    float oy = 0.25f * (a.y + (p1.y + p2.y) * rd + h3y);
    out[o] = make_float2(ox, oy);
}

// ---------------- fallback (atomic scatter path, fp32) ----------------
__global__ void init_copy(const float4* __restrict__ vsrc,
                          const float4* __restrict__ dsrc,
                          float4* __restrict__ h,
                          float4* __restrict__ acc,
                          long nv4, long total4) {
    long i = (long)blockIdx.x * blockDim.x + threadIdx.x;
    long stride = (long)gridDim.x * blockDim.x;
    for (; i < total4; i += stride) {
        float4 v = (i < nv4) ? vsrc[i] : dsrc[i - nv4];
        h[i] = v;
        acc[i] = v;
    }
}

__global__ void spmm_scatter(const int* __restrict__ erow, const int* __restrict__ ecol,
                             const float* __restrict__ eval, const float* __restrict__ h,
                             float* __restrict__ hnext, int E) {
    long tid = (long)blockIdx.x * blockDim.x + threadIdx.x;
    int e = (int)(tid >> 6);
    if (e >= E) return;
    int lane = (int)(tid & 63);
    int r = erow[e], c = ecol[e];
    float w = eval[e];
    const float2* src = reinterpret_cast<const float2*>(h + (long)c * D);
    float2 m = src[lane];
    float* dst = hnext + (long)r * D + lane * 2;
    atomicAdd(dst, w * m.x);
    atomicAdd(dst + 1, w * m.y);
}

__global__ void add_scale(float4* __restrict__ acc, const float4* __restrict__ b,
                          float s, long total4) {
    long i = (long)blockIdx.x * blockDim.x + threadIdx.x;
    long stride = (long)gridDim.x * blockDim.x;
    for (; i < total4; i += stride) {
        float4 a = acc[i];
        float4 v = b[i];
        a.x = (a.x + v.x) * s;
        a.y = (a.y + v.y) * s;
        a.z = (a.z + v.z) * s;
        a.w = (a.w + v.w) * s;
        acc[i] = a;
    }
}

extern "C" void kernel_launch(void* const* d_in, const int* in_sizes, int n_in,
                              void* d_out, int out_size, void* d_ws, size_t ws_size,
                              hipStream_t stream) {
    const int*   erow = (const int*)d_in[0];
    const int*   ecol = (const int*)d_in[1];
    const float* eval = (const float*)d_in[2];
    const float* vemb = (const float*)d_in[3];
    const float* demb = (const float*)d_in[4];

    int  E   = in_sizes[0];
    long nvD = in_sizes[3];
    long ndD = in_sizes[4];
    long ND  = nvD + ndD;
    int  N   = (int)(ND / D);
    int  nvRows = (int)(nvD / D);
    int  nbins = (N + RPB - 1) >> RPB_LOG;

    float* out = (float*)d_out;

    // ws layout (fast path)
    char* w = (char*)d_ws;
    __half* gA = (__half*)w;  w += (size_t)ND * sizeof(__half);   // g0
    __half* gB = (__half*)w;  w += (size_t)ND * sizeof(__half);   // g1
    __half* gC = (__half*)w;  w += (size_t)ND * sizeof(__half);   // g2
    int* col_s    = (int*)w;  w += (size_t)E * sizeof(int);
    int2* tmp     = (int2*)w; w += (size_t)E * sizeof(int2);
    int* row_ptr  = (int*)w;  w += (size_t)(N + 1) * sizeof(int);
    int* bin_cnt  = (int*)w;  w += MAX_BINS * sizeof(int);
    int* bin_base = (int*)w;  w += (MAX_BINS + 1) * sizeof(int);
    int* gcur     = (int*)w;  w += MAX_BINS * sizeof(int);
    float* dinv   = (float*)w; w += (size_t)N * sizeof(float);
    float* rdinv  = (float*)w; w += (size_t)N * sizeof(float);
    size_t needed = (size_t)(w - (char*)d_ws);

    long total4 = ND / 4;
    long nv4    = nvD / 4;
    const int blk = 256;
    const int copyGrid = 2048;

    if (needed <= ws_size && nbins <= MAX_BINS) {
        // ---------- CSR build (bin-local, no global row scans) ----------
        hipMemsetAsync(bin_cnt, 0, MAX_BINS * sizeof(int), stream);
        int nblkA = (E + CHUNK - 1) / CHUNK;
        hipLaunchKernelGGL(binCount, dim3(nblkA), dim3(256), 0, stream,
                           erow, bin_cnt, E, nbins);
        hipLaunchKernelGGL(scanBins, dim3(1), dim3(1024), 0, stream,
                           bin_cnt, bin_base, gcur, nbins, E);
        hipLaunchKernelGGL(binA, dim3(nblkA), dim3(256), 0, stream,
                           erow, ecol, gcur, tmp, E, nbins);
        hipLaunchKernelGGL(binB, dim3(nbins), dim3(RPB), 0, stream,
                           tmp, bin_base, row_ptr, dinv, rdinv, col_s, N, E, nbins);

        // ---------- init: g0 = fp16(dinv*x) ----------
        hipLaunchKernelGGL(init_g, dim3(copyGrid), dim3(blk), 0, stream,
                           (const float4*)vemb, (const float4*)demb, dinv,
                           (__half2*)gA, nv4, total4);

        // ---------- layers ----------
        int rgrid = (int)(((long)N * 64 + blk - 1) / blk);
        // L1: g0 -> g1
        hipLaunchKernelGGL(spmm_mid, dim3(rgrid), dim3(blk), 0, stream,
                           row_ptr, col_s, dinv, (const __half2*)gA,
                           (__half2*)gB, N);
        // L2: g1 -> g2
        hipLaunchKernelGGL(spmm_mid, dim3(rgrid), dim3(blk), 0, stream,
                           row_ptr, col_s, dinv, (const __half2*)gB,
                           (__half2*)gC, N);
        // L3 fused epilogue: gather from g2; out = 0.25*(x + (g1+g2)*rdinv + h3)
        hipLaunchKernelGGL(spmm_final, dim3(rgrid), dim3(blk), 0, stream,
                           row_ptr, col_s, dinv, rdinv,
                           (const __half2*)gC, (const __half2*)gB,
                           (const float2*)vemb, (const float2*)demb,
                           nvRows, (float2*)out, N);
    } else {
        // ---------- fallback: atomic scatter path (fp32) ----------
        float* bufA = (float*)d_ws;
        float* bufB = bufA + ND;
        hipLaunchKernelGGL(init_copy, dim3(copyGrid), dim3(blk), 0, stream,
                           (const float4*)vemb, (const float4*)demb,
                           (float4*)bufA, (float4*)out, nv4, total4);
        float* cur = bufA;
        float* nxt = bufB;
        for (int l = 0; l < 3; ++l) {
            hipMemsetAsync(nxt, 0, (size_t)ND * sizeof(float), stream);
            long threads = (long)E * 64;
            int  sgrid   = (int)((threads + blk - 1) / blk);
            hipLaunchKernelGGL(spmm_scatter, dim3(sgrid), dim3(blk), 0, stream,
                               erow, ecol, eval, cur, nxt, E);
            float s = (l == 2) ? 0.25f : 1.0f;
            hipLaunchKernelGGL(add_scale, dim3(copyGrid), dim3(blk), 0, stream,
                               (float4*)out, (const float4*)nxt, s, total4);
            float* t = cur; cur = nxt; nxt = t;
        }
    }
}